// Round 10
// baseline (108.682 us; speedup 1.0000x reference)
//
#include <hip/hip_runtime.h>
#include <math.h>

// RWKV WKV forward — chunked scan, NCC=256 chunks of LL=16, hierarchical prefix.
// Round-10: pass1 rebuilt around global_load_lds DMA (no VGPR dependency ->
// compiler cannot serialize the load queue; rounds 1-9 proved VGPR-destined
// loads always collapse to ~1 in flight). Persistent blocks (grid=256, one
// per CU, 96 KB LDS), 8 chunks/block, double-buffered 8-row halves with
// counted vmcnt(16) + raw s_barrier (T3/T4 pattern).

#define NEG_INF (-1e38f)
#define NCC 256          // chunks per sequence
#define SCW 16           // chunks per superchunk
#define NSC (NCC / SCW)  // superchunks
#define LL  16           // timesteps per chunk (T=4096/NCC)
#define CH  768          // channels (C)
#define HALFF 6144       // floats per half-chunk (8 rows * 768)

typedef float f4 __attribute__((ext_vector_type(4)));

__device__ __forceinline__ void wkv_step(float& aa, float& bb, float& pp,
                                         float wc, float kt, float vt) {
    float ww = wc + pp;
    float p  = fmaxf(ww, kt);
    float d  = ww - kt;
    float e  = __expf(-fabsf(d));
    float e1 = (d >= 0.f) ? 1.f : e;
    float e2 = (d >= 0.f) ? e   : 1.f;
    aa = e1 * aa + e2 * vt;
    bb = e1 * bb + e2;
    pp = p;
}

__device__ __forceinline__ float wkv_ostep(float aa, float bb, float pp,
                                           float uc, float kt, float vt) {
    float ww = uc + kt;
    float d  = pp - ww;
    float e  = __expf(-fabsf(d));
    float e1 = (d >= 0.f) ? 1.f : e;
    float e2 = (d >= 0.f) ? e   : 1.f;
    return __fdividef(e1 * aa + e2 * vt, e1 * bb + e2);
}

__device__ __forceinline__ void wkv_combine(float& aa, float& bb, float& pp,
                                            float dw, float la, float lb, float lp) {
    float ppd = pp + dw;
    float p   = fmaxf(ppd, lp);
    float e1  = __expf(ppd - p);
    float e2  = __expf(lp - p);
    aa = e1 * aa + e2 * la;
    bb = e1 * bb + e2 * lb;
    pp = p;
}

// Async DMA global->LDS, 16 B per lane. Global src is per-lane; LDS dest is
// wave-uniform base (hardware adds lane*16).
__device__ __forceinline__ void gld16(const float* g, float* l) {
    __builtin_amdgcn_global_load_lds(
        (const __attribute__((address_space(1))) unsigned int*)g,
        (__attribute__((address_space(3))) unsigned int*)l, 16, 0, 0);
}

// ---------------------------------------------------------------------------
// Pass 1: persistent. grid=256 (1 block/CU via 96 KB LDS), 192 threads,
// 4 adjacent channels/thread. Each block scans 8 consecutive chunks; each
// chunk = 2 halves of 8 rows. Pipeline: issue DMA(half H+1) -> vmcnt(16)
// -> barrier -> compute(half H) -> barrier.
__global__ __launch_bounds__(192)
void wkv_pass1(const float* __restrict__ w,
               const float* __restrict__ kg,
               const float* __restrict__ vg,
               float* __restrict__ sa, float* __restrict__ sb,
               float* __restrict__ sp,
               int B, int T, int C) {
    __shared__ float ldsk[2 * HALFF];    // 48 KB
    __shared__ float ldsv[2 * HALFF];    // 48 KB
    const int tid = threadIdx.x;
    const int wv  = tid >> 6;            // wave 0..2
    const int l   = tid & 63;
    const int g0  = blockIdx.x * 8;      // first flattened chunk (b*NCC+j)
    const int BC  = B * C;

    f4 wc = *(const f4*)(w + 4 * tid);
    asm volatile("" :: "v"(wc));         // drain wc's load before DMA issue

    // Issue DMA for half H (16 instrs/wave: 8 k + 8 v, 1 KB each).
    auto issue = [&](int H) {
        const int g  = g0 + (H >> 1);
        const int bb = g >> 8;                        // NCC = 256
        const int jj = g & 255;
        const int ro = (H & 1) * 8;                   // row offset in chunk
        const float* gk = kg + ((size_t)bb * T + (size_t)jj * LL + ro) * CH;
        const float* gv = vg + ((size_t)bb * T + (size_t)jj * LL + ro) * CH;
        float* lk = ldsk + (H & 1) * HALFF;
        float* lv = ldsv + (H & 1) * HALFF;
        #pragma unroll
        for (int i = 0; i < 8; ++i) {
            const int idx = 8 * wv + i;               // 0..23: floats [256idx,256idx+256)
            gld16(gk + 256 * idx + 4 * l, lk + 256 * idx);
            gld16(gv + 256 * idx + 4 * l, lv + 256 * idx);
        }
    };

    issue(0);

    float aa[4], bq[4], pp[4];
    for (int h = 0; h < 16; ++h) {
        if (h < 15) {
            issue(h + 1);
            asm volatile("s_waitcnt vmcnt(16)" ::: "memory");  // half h landed
        } else {
            asm volatile("s_waitcnt vmcnt(0)" ::: "memory");
        }
        __builtin_amdgcn_sched_barrier(0);
        __builtin_amdgcn_s_barrier();
        __builtin_amdgcn_sched_barrier(0);

        if ((h & 1) == 0) {              // new chunk: reset state
            #pragma unroll
            for (int q = 0; q < 4; ++q) { aa[q] = 0.f; bq[q] = 0.f; pp[q] = NEG_INF; }
        }
        const float* lk = ldsk + (h & 1) * HALFF;
        const float* lv = ldsv + (h & 1) * HALFF;
        #pragma unroll
        for (int tt = 0; tt < 8; ++tt) {
            f4 kk = *(const f4*)(lk + tt * CH + 4 * tid);
            f4 vv = *(const f4*)(lv + tt * CH + 4 * tid);
            #pragma unroll
            for (int q = 0; q < 4; ++q) {
                float kt = kk[q], vt = vv[q];
                wkv_step(aa[q], bq[q], pp[q], wc[q], kt, vt);
            }
        }
        if (h & 1) {                     // chunk done: store summary
            const int g  = g0 + (h >> 1);
            const int bb = g >> 8;
            const int jj = g & 255;
            const int base = jj * BC + bb * C + 4 * tid;
            f4 oa = {aa[0], aa[1], aa[2], aa[3]};
            f4 ob = {bq[0], bq[1], bq[2], bq[3]};
            f4 op = {pp[0], pp[1], pp[2], pp[3]};
            *(f4*)(sa + base) = oa;
            *(f4*)(sb + base) = ob;
            *(f4*)(sp + base) = op;
        }
        __builtin_amdgcn_sched_barrier(0);
        __builtin_amdgcn_s_barrier();    // protect buffer from next overwrite
    }
}

// ---------------------------------------------------------------------------
// Scan 2a: inclusive scan of SCW chunk summaries inside each superchunk,
// in place. One thread per (channel, superchunk). Load-all-then-store.
__global__ void wkv_scan_local(const float* __restrict__ w,
                               float* __restrict__ sa, float* __restrict__ sb,
                               float* __restrict__ sp,
                               int B, int C) {
    const int BC = B * C;
    int tid = blockIdx.x * blockDim.x + threadIdx.x;
    if (tid >= BC * NSC) return;
    const int bc = tid % BC;
    const int sc = tid / BC;
    const float wL = w[bc % C] * (float)LL;

    float la[SCW], lb[SCW], lp[SCW];
    #pragma unroll
    for (int i = 0; i < SCW; ++i) {
        const int idx = (sc * SCW + i) * BC + bc;
        la[i] = sa[idx]; lb[i] = sb[idx]; lp[i] = sp[idx];
    }
    float aa = 0.f, bb = 0.f, pp = NEG_INF;
    #pragma unroll
    for (int i = 0; i < SCW; ++i) {
        wkv_combine(aa, bb, pp, wL, la[i], lb[i], lp[i]);
        const int idx = (sc * SCW + i) * BC + bc;
        sa[idx] = aa; sb[idx] = bb; sp[idx] = pp;
    }
}

// ---------------------------------------------------------------------------
// Scan 2b: exclusive scan over superchunk totals (in each superchunk's last
// chunk slot); overwrite those slots with the superchunk carry-in E_sc.
__global__ void wkv_scan_super(const float* __restrict__ w,
                               float* __restrict__ sa, float* __restrict__ sb,
                               float* __restrict__ sp,
                               int B, int C) {
    const int BC = B * C;
    int bc = blockIdx.x * blockDim.x + threadIdx.x;
    if (bc >= BC) return;
    const float wSL = w[bc % C] * (float)(LL * SCW);

    float ta[NSC], tb[NSC], tp[NSC];
    #pragma unroll
    for (int sc = 0; sc < NSC; ++sc) {
        const int idx = (sc * SCW + (SCW - 1)) * BC + bc;
        ta[sc] = sa[idx]; tb[sc] = sb[idx]; tp[sc] = sp[idx];
    }
    float aa = 0.f, bb = 0.f, pp = NEG_INF;
    #pragma unroll
    for (int sc = 0; sc < NSC; ++sc) {
        const int idx = (sc * SCW + (SCW - 1)) * BC + bc;
        sa[idx] = aa; sb[idx] = bb; sp[idx] = pp;       // E_sc (exclusive)
        wkv_combine(aa, bb, pp, wSL, ta[sc], tb[sc], tp[sc]);
    }
}

// ---------------------------------------------------------------------------
// Pass 3: carry-in for chunk j = decay(E_sc, i*LL*w) (+) incl(j-1); replay
// chunk, emit y with 16-byte nt stores. (k,v are L3-hot after pass1 -> fast.)
__global__ __launch_bounds__(192)
void wkv_pass3(const float* __restrict__ w, const float* __restrict__ u,
               const float* __restrict__ kg, const float* __restrict__ vg,
               const float* __restrict__ sa, const float* __restrict__ sb,
               const float* __restrict__ sp,
               float* __restrict__ y,
               int B, int T, int C) {
    const int b   = blockIdx.x / NCC;
    const int j   = blockIdx.x % NCC;
    const int tid = threadIdx.x;
    const int C4  = C >> 2;
    const int BC  = B * C;

    const size_t rowbase = ((size_t)b * T + (size_t)j * LL) * C;
    const f4* kp = (const f4*)(kg + rowbase) + tid;
    const f4* vp = (const f4*)(vg + rowbase) + tid;
    f4*       yp = (f4*)(y + rowbase) + tid;
    const f4  wc = ((const f4*)w)[tid];
    const f4  uc = ((const f4*)u)[tid];

    f4 kb[LL], vb[LL];
    #pragma unroll
    for (int t = 0; t < LL; ++t) { kb[t] = kp[t * C4]; vb[t] = vp[t * C4]; }

    const int sc = j / SCW;
    const int i  = j % SCW;
    const int slot_last = (sc * SCW + (SCW - 1)) * BC + b * C;
    f4 Ea = ((const f4*)(sa + slot_last))[tid];
    f4 Eb = ((const f4*)(sb + slot_last))[tid];
    f4 Ep = ((const f4*)(sp + slot_last))[tid];

    float aa[4], bb[4], pp[4];
    if (i == 0) {                       // block-uniform branch
        #pragma unroll
        for (int q = 0; q < 4; ++q) { aa[q] = Ea[q]; bb[q] = Eb[q]; pp[q] = Ep[q]; }
    } else {
        const int prev = (j - 1) * BC + b * C;
        f4 la = ((const f4*)(sa + prev))[tid];
        f4 lb = ((const f4*)(sb + prev))[tid];
        f4 lp = ((const f4*)(sp + prev))[tid];
        const float steps = (float)(i * LL);
        #pragma unroll
        for (int q = 0; q < 4; ++q) {
            float a = Ea[q], bq = Eb[q], p = Ep[q];
            wkv_combine(a, bq, p, wc[q] * steps, la[q], lb[q], lp[q]);
            aa[q] = a; bb[q] = bq; pp[q] = p;
        }
    }

    #pragma unroll
    for (int t = 0; t < LL; ++t) {
        f4 yo;
        #pragma unroll
        for (int q = 0; q < 4; ++q) {
            float kt = kb[t][q], vt = vb[t][q];
            yo[q] = wkv_ostep(aa[q], bb[q], pp[q], uc[q], kt, vt);
            wkv_step(aa[q], bb[q], pp[q], wc[q], kt, vt);
        }
        __builtin_nontemporal_store(yo, yp + t * C4);
    }
}

// ---------------------------------------------------------------------------
extern "C" void kernel_launch(void* const* d_in, const int* in_sizes, int n_in,
                              void* d_out, int out_size, void* d_ws, size_t ws_size,
                              hipStream_t stream) {
    // inputs: 0=B 1=T 2=C 3=w 4=u 5=k 6=v
    const float* w = (const float*)d_in[3];
    const float* u = (const float*)d_in[4];
    const float* k = (const float*)d_in[5];
    const float* v = (const float*)d_in[6];
    float* y = (float*)d_out;

    const int C  = in_sizes[3];          // 768
    const int BT = in_sizes[5] / C;      // B*T
    const int T  = 4096;                 // fixed problem instance (T = NCC*LL)
    const int B  = BT / T;               // 8

    const int BC = B * C;
    const size_t total = (size_t)BC * NCC;
    float* sa = (float*)d_ws;
    float* sb = sa + total;
    float* sp = sb + total;

    // pass1: persistent, 8 chunks per block
    wkv_pass1<<<(B * NCC) / 8, C / 4, 0, stream>>>(w, k, v, sa, sb, sp, B, T, C);

    const int n2 = BC * NSC;
    wkv_scan_local<<<(n2 + 255) / 256, 256, 0, stream>>>(w, sa, sb, sp, B, C);
    wkv_scan_super<<<(BC + 255) / 256, 256, 0, stream>>>(w, sa, sb, sp, B, C);

    wkv_pass3<<<B * NCC, C / 4, 0, stream>>>(w, u, k, v, sa, sb, sp, y, B, T, C);
}